// Round 5
// baseline (125.916 us; speedup 1.0000x reference)
//
#include <hip/hip_runtime.h>

#define N_EP     4096     // 2048 lines * 2 endpoints
#define NLINES   2048
#define KPTS     2048
#define CCH      256
#define HC_      128
#define WC_      128
#define NPTS_ALL 6144     // N_EP + KPTS
#define GRID_W   128      // 8-px cells over 1024-px image
#define NCELL    (GRID_W * GRID_W)

// ---- output chunk offsets (floats) ----
#define O_PTS  0          // all_points (1,6144,2)       12288
#define O_SC   12288      // all_scores (1,6144)          6144
#define O_DESC 18432      // all_descs (1,256,6144)    1572864
#define O_NL   1591296    // new_lines (1,2048,2,2)       8192
#define O_LJI  1599488    // lines_junc_idx (1,2048,2)    4096
#define O_LS   1603584    // ls (1,2048)                  2048

// ---- ws offsets (4-byte words) ----
#define W_JUNC 0          // float[8192] (x,y interleaved)
#define W_KEEP 8192       // int[2048]
#define W_V    10240      // float[256*4096] unnormalized junction descs

// ============================================================================
// K_ALL: one block does everything except descriptor sampling.
// LDS grid (8-px cells): count -> scan -> scatter; then all neighbor queries
// are 3x3-cell scans (eps=3 and r=4 both < 8). Phases:
//   P0 ls-normalize | P1-P4 build grid | P5 min-label propagation
//   P6 kp suppression | P7 dense rank | P8 segment sums | P9 means | P10 lines
// Dynamic LDS words: s_ls[2048] cellEnd[16384] sorted[4096] lab[4096] = 104 KB
// Overlays after grid is dead: fcnt/fsx/fsy/fss over cellEnd, rnk over sorted.
// ============================================================================
__global__ __launch_bounds__(1024) void k_all(
    const float2* __restrict__ ep, const float2* __restrict__ kpts,
    const float* __restrict__ ksc, const float* __restrict__ lsc,
    float* __restrict__ junc, int* __restrict__ keep_ws,
    float* __restrict__ out_pts, float* __restrict__ out_sc,
    float* __restrict__ out_nl, float* __restrict__ out_lji,
    float* __restrict__ out_ls) {
    extern __shared__ int smem[];
    float* s_ls    = (float*)smem;                       // 2048
    int*   cellEnd = smem + 2048;                        // 16384
    int*   sorted  = smem + 2048 + 16384;                // 4096
    int*   lab     = smem + 2048 + 16384 + 4096;         // 4096
    float* fcnt = (float*)cellEnd;                       // overlay (grid dead)
    float* fsx  = (float*)(cellEnd + 4096);
    float* fsy  = (float*)(cellEnd + 8192);
    float* fss  = (float*)(cellEnd + 12288);
    int*   rnk  = sorted;                                // overlay
    __shared__ float redf[16];
    __shared__ int wsum[16];
    __shared__ int changed;

    int t = threadIdx.x;
    int lane = t & 63, wv = t >> 6;

    // ---- P0: ls = line_scores / (1e-8 + max) ----
    float mx = -1e30f;
    for (int i = t; i < NLINES; i += 1024) mx = fmaxf(mx, lsc[i]);
    for (int off = 32; off > 0; off >>= 1) mx = fmaxf(mx, __shfl_down(mx, off));
    if (lane == 0) redf[wv] = mx;
    __syncthreads();
    if (t == 0) {
        float mm = redf[0];
        for (int w = 1; w < 16; w++) mm = fmaxf(mm, redf[w]);
        redf[0] = 1e-8f + mm;
    }
    __syncthreads();
    float denom = redf[0];
    for (int i = t; i < NLINES; i += 1024) {
        float v = lsc[i] / denom;
        s_ls[i] = v;
        out_ls[i] = v;
    }
    // ---- P1: zero cell counts ----
    for (int i = t; i < NCELL; i += 1024) cellEnd[i] = 0;
    __syncthreads();
    // ---- P2: count points per cell ----
    for (int i = t; i < N_EP; i += 1024) {
        float2 p = ep[i];
        int cx = (int)(p.x * 0.125f), cy = (int)(p.y * 0.125f);
        atomicAdd(&cellEnd[cy * GRID_W + cx], 1);
    }
    __syncthreads();
    // ---- P3: exclusive scan over 16384 cells (16/thread, reg-held) ----
    {
        int base = t * 16;
        int loc[16];
        int s = 0;
        #pragma unroll
        for (int q = 0; q < 16; q++) { loc[q] = cellEnd[base + q]; s += loc[q]; }
        int v = s;
        for (int off = 1; off < 64; off <<= 1) {
            int u = __shfl_up(v, off);
            if (lane >= off) v += u;
        }
        if (lane == 63) wsum[wv] = v;
        __syncthreads();
        if (wv == 0 && lane < 16) {
            int w = wsum[lane];
            for (int off = 1; off < 16; off <<= 1) {
                int u = __shfl_up(w, off);
                if (lane >= off) w += u;
            }
            wsum[lane] = w;
        }
        __syncthreads();
        int run = ((wv == 0) ? 0 : wsum[wv - 1]) + v - s;
        #pragma unroll
        for (int q = 0; q < 16; q++) { cellEnd[base + q] = run; run += loc[q]; }
    }
    __syncthreads();
    // ---- P4: scatter (cellEnd[c] becomes end-of-cell; start = cellEnd[c-1]) ----
    for (int i = t; i < N_EP; i += 1024) {
        float2 p = ep[i];
        int cx = (int)(p.x * 0.125f), cy = (int)(p.y * 0.125f);
        int pos = atomicAdd(&cellEnd[cy * GRID_W + cx], 1);
        sorted[pos] = i;
    }
    for (int i = t; i < N_EP; i += 1024) lab[i] = i;
    __syncthreads();
    // ---- P5: min-label propagation via 3x3 grid scans + pointer jumping ----
    for (int it = 0; it < 64; ++it) {
        __syncthreads();
        if (t == 0) changed = 0;
        __syncthreads();
        int f = 0;
        for (int i = t; i < N_EP; i += 1024) {
            float2 p = ep[i];
            int cx = (int)(p.x * 0.125f), cy = (int)(p.y * 0.125f);
            int ml = lab[i];
            int yl = max(cy - 1, 0), yh = min(cy + 1, GRID_W - 1);
            int xl = max(cx - 1, 0), xh = min(cx + 1, GRID_W - 1);
            for (int yy = yl; yy <= yh; ++yy)
                for (int xx = xl; xx <= xh; ++xx) {
                    int cell = yy * GRID_W + xx;
                    int st = cell ? cellEnd[cell - 1] : 0;
                    int en = cellEnd[cell];
                    for (int q = st; q < en; ++q) {
                        int j = sorted[q];
                        float2 pj = ep[j];
                        float dx = p.x - pj.x, dy = p.y - pj.y;
                        if (dx * dx + dy * dy <= 9.0f) ml = min(ml, lab[j]);
                    }
                }
            ml = min(ml, lab[ml]);        // pointer jump (lab[k] <= k invariant)
            if (ml < lab[i]) { lab[i] = ml; f = 1; }
        }
        if (f) atomicOr(&changed, 1);
        __syncthreads();
        if (changed == 0) break;
    }
    __syncthreads();
    // ---- P6: keypoint suppression via same grid (r=4 < 8) ----
    for (int k = t; k < KPTS; k += 1024) {
        float2 p = kpts[k];
        int cx = (int)(p.x * 0.125f), cy = (int)(p.y * 0.125f);
        int yl = max(cy - 1, 0), yh = min(cy + 1, GRID_W - 1);
        int xl = max(cx - 1, 0), xh = min(cx + 1, GRID_W - 1);
        int hit = 0;
        for (int yy = yl; yy <= yh && !hit; ++yy)
            for (int xx = xl; xx <= xh && !hit; ++xx) {
                int cell = yy * GRID_W + xx;
                int st = cell ? cellEnd[cell - 1] : 0;
                int en = cellEnd[cell];
                for (int q = st; q < en; ++q) {
                    int j = sorted[q];
                    float2 pj = ep[j];
                    float dx = p.x - pj.x, dy = p.y - pj.y;
                    if (dx * dx + dy * dy < 16.0f) { hit = 1; break; }
                }
            }
        int keep = !hit;
        keep_ws[k] = keep;
        out_pts[2 * (N_EP + k)] = keep ? p.x : 0.f;
        out_pts[2 * (N_EP + k) + 1] = keep ? p.y : 0.f;
        out_sc[N_EP + k] = keep ? ksc[k] : 0.f;
    }
    __syncthreads();   // grid (cellEnd/sorted) dead beyond here
    // ---- P7: dense rank of roots (rnk overlays sorted) ----
    for (int i = t; i < N_EP; i += 1024) rnk[i] = 0;
    __syncthreads();
    for (int i = t; i < N_EP; i += 1024) rnk[lab[i]] = 1;
    __syncthreads();
    {
        int b4 = t * 4;
        int a0 = rnk[b4], a1 = rnk[b4 + 1], a2 = rnk[b4 + 2], a3 = rnk[b4 + 3];
        int s = a0 + a1 + a2 + a3;
        int v = s;
        for (int off = 1; off < 64; off <<= 1) {
            int u = __shfl_up(v, off);
            if (lane >= off) v += u;
        }
        if (lane == 63) wsum[wv] = v;
        __syncthreads();
        if (wv == 0 && lane < 16) {
            int w = wsum[lane];
            for (int off = 1; off < 16; off <<= 1) {
                int u = __shfl_up(w, off);
                if (lane >= off) w += u;
            }
            wsum[lane] = w;
        }
        __syncthreads();
        int excl = ((wv == 0) ? 0 : wsum[wv - 1]) + v - s;
        rnk[b4] = excl;
        rnk[b4 + 1] = excl + a0;
        rnk[b4 + 2] = excl + a0 + a1;
        rnk[b4 + 3] = excl + a0 + a1 + a2;
    }
    __syncthreads();
    // ---- P8: relabel + LDS segment sums (f-arrays overlay cellEnd) ----
    for (int i = t; i < N_EP; i += 1024) {
        fcnt[i] = 0.f; fsx[i] = 0.f; fsy[i] = 0.f; fss[i] = 0.f;
    }
    __syncthreads();
    for (int i = t; i < N_EP; i += 1024) {
        int c = rnk[lab[i]];
        out_lji[i] = (float)c;
        float2 p = ep[i];
        atomicAdd(&fcnt[c], 1.f);
        atomicAdd(&fsx[c], p.x);
        atomicAdd(&fsy[c], p.y);
        atomicAdd(&fss[c], s_ls[i >> 1]);
        lab[i] = c;                       // lab now holds cluster id
    }
    __syncthreads();
    // ---- P9: segment means -> junction outputs ----
    for (int j = t; j < N_EP; j += 1024) {
        float cm = fmaxf(fcnt[j], 1.f);
        float jx = fsx[j] / cm, jy = fsy[j] / cm;
        fsx[j] = jx; fsy[j] = jy;
        junc[2 * j] = jx; junc[2 * j + 1] = jy;
        out_pts[2 * j] = jx; out_pts[2 * j + 1] = jy;
        out_sc[j] = fss[j] / cm;
    }
    __syncthreads();
    // ---- P10: new_lines = junctions[clusters] ----
    for (int e = t; e < N_EP; e += 1024) {
        int c = lab[e];
        out_nl[2 * e] = fsx[c];
        out_nl[2 * e + 1] = fsy[c];
    }
}

// ============================================================================
// K_SAMP: bilinear sample, one block per channel, plane staged in LDS.
// 1024 threads (16 waves/CU) for latency hiding; no atomics.
// ============================================================================
__global__ __launch_bounds__(1024) void k_samp(const float* __restrict__ ad,
                                               const float* __restrict__ junc,
                                               float* __restrict__ v_ws) {
    __shared__ float plane[HC_ * WC_];   // 64 KB
    int c = blockIdx.x, t = threadIdx.x;
    const float4* s4 = (const float4*)(ad + c * (HC_ * WC_));
    float4* p4 = (float4*)plane;
    #pragma unroll
    for (int i = 0; i < 4; ++i) p4[t + i * 1024] = s4[t + i * 1024];
    __syncthreads();
    const float2* j2 = (const float2*)junc;
    #pragma unroll
    for (int k = 0; k < 4; ++k) {
        int m = t + k * 1024;
        float2 pj = j2[m];
        float gx = (pj.x - 3.5f) / 1019.5f * 2.f - 1.f;
        float gy = (pj.y - 3.5f) / 1019.5f * 2.f - 1.f;
        float x = (gx + 1.f) * 0.5f * (WC_ - 1);
        float y = (gy + 1.f) * 0.5f * (HC_ - 1);
        float x0f = fminf(fmaxf(floorf(x), 0.f), WC_ - 1);
        float y0f = fminf(fmaxf(floorf(y), 0.f), HC_ - 1);
        float x1f = fminf(x0f + 1.f, WC_ - 1);
        float y1f = fminf(y0f + 1.f, HC_ - 1);
        float wx = x - x0f, wy = y - y0f;
        int x0 = (int)x0f, x1 = (int)x1f, y0 = (int)y0f, y1 = (int)y1f;
        float v = plane[y0 * WC_ + x0] * (1.f - wx) * (1.f - wy)
                + plane[y0 * WC_ + x1] * wx * (1.f - wy)
                + plane[y1 * WC_ + x0] * (1.f - wx) * wy
                + plane[y1 * WC_ + x1] * wx * wy;
        v_ws[c * N_EP + m] = v;
    }
}

// ============================================================================
// K_EPI: blocks [0,64): 256ch x 64junc LDS tile — column norms + normalize,
// one coalesced pass, no atomics. Blocks [64,576): float4 kp-desc copy.
// ============================================================================
__global__ __launch_bounds__(256) void k_epi(const float* __restrict__ v_ws,
                                             const float* __restrict__ desc,
                                             const int* __restrict__ keep,
                                             float* __restrict__ out_desc) {
    __shared__ float tile[CCH][64];
    __shared__ float partial[4][64];
    __shared__ float inv[64];
    int b = blockIdx.x, t = threadIdx.x;
    if (b < 64) {
        int m0 = b * 64;
        int q = t >> 6, ml = t & 63;
        // load: 4 channel-rows per iteration, 64-wide coalesced
        for (int cc = 0; cc < 64; ++cc) {
            int c = cc * 4 + q;
            tile[c][ml] = v_ws[c * N_EP + m0 + ml];
        }
        __syncthreads();
        float s = 0.f;
        for (int c = q * 64; c < q * 64 + 64; ++c) {
            float v = tile[c][ml];
            s += v * v;
        }
        partial[q][ml] = s;
        __syncthreads();
        if (t < 64) {
            float tot = partial[0][t] + partial[1][t] + partial[2][t] + partial[3][t];
            inv[t] = 1.f / fmaxf(sqrtf(tot), 1e-12f);
        }
        __syncthreads();
        for (int cc = 0; cc < 64; ++cc) {
            int c = cc * 4 + q;
            out_desc[c * NPTS_ALL + m0 + ml] = tile[c][ml] * inv[ml];
        }
    } else {
        int gid = (b - 64) * 256 + t;        // 131072 float4 groups
        int c = gid >> 9;                    // 512 groups per channel
        int k4 = (gid & 511) * 4;
        float4 d = *(const float4*)(desc + c * KPTS + k4);
        float4 o;
        o.x = keep[k4]     ? d.x : 0.f;
        o.y = keep[k4 + 1] ? d.y : 0.f;
        o.z = keep[k4 + 2] ? d.z : 0.f;
        o.w = keep[k4 + 3] ? d.w : 0.f;
        *(float4*)(out_desc + c * NPTS_ALL + N_EP + k4) = o;
    }
}

extern "C" void kernel_launch(void* const* d_in, const int* in_sizes, int n_in,
                              void* d_out, int out_size, void* d_ws, size_t ws_size,
                              hipStream_t stream) {
    const float* lines    = (const float*)d_in[0];   // (1,2048,2,2) == endpoints (4096,2)
    const float* lscores  = (const float*)d_in[1];   // (1,2048)
    const float* kpts     = (const float*)d_in[2];   // (1,2048,2)
    const float* kscores  = (const float*)d_in[3];   // (1,2048)
    const float* descs    = (const float*)d_in[4];   // (1,256,2048)
    const float* alldesc  = (const float*)d_in[5];   // (1,256,128,128)
    float* out = (float*)d_out;

    float* wf   = (float*)d_ws;
    int*   wi   = (int*)d_ws;
    float* junc = wf + W_JUNC;
    int*   keep = wi + W_KEEP;
    float* v_ws = wf + W_V;

    size_t lds_bytes = (size_t)(2048 + NCELL + N_EP + N_EP) * sizeof(int);  // 104 KB
    k_all<<<1, 1024, lds_bytes, stream>>>(
        (const float2*)lines, (const float2*)kpts, kscores, lscores,
        junc, keep, out + O_PTS, out + O_SC, out + O_NL, out + O_LJI, out + O_LS);

    k_samp<<<CCH, 1024, 0, stream>>>(alldesc, junc, v_ws);

    k_epi<<<64 + 512, 256, 0, stream>>>(v_ws, descs, keep, out + O_DESC);
}

// Round 6
// 66.618 us; speedup vs baseline: 1.8901x; 1.8901x over previous
//
#include <hip/hip_runtime.h>

#define N_EP     4096     // 2048 lines * 2 endpoints
#define NLINES   2048
#define KPTS     2048
#define CCH      256
#define HC_      128
#define WC_      128
#define MAXNBR   16
#define NPTS_ALL 6144     // N_EP + KPTS

// ---- output chunk offsets (floats) ----
#define O_PTS  0          // all_points (1,6144,2)       12288
#define O_SC   12288      // all_scores (1,6144)          6144
#define O_DESC 18432      // all_descs (1,256,6144)    1572864
#define O_NL   1591296    // new_lines (1,2048,2,2)       8192
#define O_LJI  1599488    // lines_junc_idx (1,2048,2)    4096
#define O_LS   1603584    // ls (1,2048)                  2048

// ---- ws offsets (4-byte words) ----
#define W_LS   0          // float[2048]
#define W_DEG  2048       // int[4096]
#define W_NBR  6144       // int[4096*16]
#define W_KEEP 71680      // int[2048]
#define W_JUNC 73728      // float[8192] (x,y interleaved)
#define W_V    81920      // float[256*4096] unnormalized junction descs

// ============================================================================
// K_FRONT: all input-only massively-parallel work.
//   blocks [0,4096)    : neighbor lists of eps<=3 ball graph (1 blk/point)
//   blocks [4096,6144) : keypoint suppression (1 blk/keypoint)
//   block  6144        : ls normalize
// ============================================================================
__global__ __launch_bounds__(256) void k_front(
    const float2* __restrict__ ep, const float2* __restrict__ kpts,
    const float* __restrict__ ksc, const float* __restrict__ lsc,
    int* __restrict__ deg, int* __restrict__ nbr, int* __restrict__ keep_ws,
    float* __restrict__ ws_ls,
    float* __restrict__ out_pts, float* __restrict__ out_sc,
    float* __restrict__ out_ls) {
    __shared__ float red[256];
    __shared__ int flag;
    int b = blockIdx.x, t = threadIdx.x;

    if (b < N_EP) {                       // ---- neighbor lists ----
        if (t == 0) flag = 0;
        __syncthreads();
        float2 p = ep[b];
        for (int j = t; j < N_EP; j += 256) {
            if (j == b) continue;
            float2 q = ep[j];
            float dx = p.x - q.x, dy = p.y - q.y;
            if (dx * dx + dy * dy <= 9.0f) {
                int s = atomicAdd(&flag, 1);
                if (s < MAXNBR) nbr[b * MAXNBR + s] = j;
            }
        }
        __syncthreads();
        if (t == 0) deg[b] = min(flag, MAXNBR);
    } else if (b < N_EP + KPTS) {         // ---- keypoint suppression ----
        int k = b - N_EP;
        if (t == 0) flag = 0;
        __syncthreads();
        float2 p = kpts[k];
        int hit = 0;
        for (int j = t; j < N_EP; j += 256) {
            float2 q = ep[j];
            float dx = p.x - q.x, dy = p.y - q.y;
            if (dx * dx + dy * dy < 16.0f) hit = 1;
        }
        if (__any(hit) && (t & 63) == 0) atomicOr(&flag, 1);
        __syncthreads();
        if (t == 0) {
            int keep = !flag;
            keep_ws[k] = keep;
            out_pts[2 * (N_EP + k)] = keep ? p.x : 0.f;
            out_pts[2 * (N_EP + k) + 1] = keep ? p.y : 0.f;
            out_sc[N_EP + k] = keep ? ksc[k] : 0.f;
        }
    } else {                              // ---- ls ----
        float m = -1e30f;
        for (int i = t; i < NLINES; i += 256) m = fmaxf(m, lsc[i]);
        red[t] = m; __syncthreads();
        for (int s = 128; s > 0; s >>= 1) {
            if (t < s) red[t] = fmaxf(red[t], red[t + s]);
            __syncthreads();
        }
        float denom = 1e-8f + red[0];
        for (int i = t; i < NLINES; i += 256) {
            float v = lsc[i] / denom;
            ws_ls[i] = v;
            out_ls[i] = v;
        }
    }
}

// ============================================================================
// K_CLUSTER: single-block connected components on precomputed nbr lists +
// dense relabel + all junction outputs via LDS segment sums.
// deg staged in LDS; nbr read from global only for the ~3% deg>0 points.
// Dynamic LDS (ints): lab[4096] rnk[4096] deg_s[4096] fcnt[4096] fsx[4096]
//                     fsy[4096] fss[4096]  = 112 KB
// ============================================================================
__global__ __launch_bounds__(1024) void k_cluster(
    const float2* __restrict__ ep, const int* __restrict__ deg,
    const int* __restrict__ nbr, const float* __restrict__ ws_ls,
    float* __restrict__ junc, float* __restrict__ out_pts,
    float* __restrict__ out_sc, float* __restrict__ out_nl,
    float* __restrict__ out_lji) {
    extern __shared__ int smem[];
    int*   lab   = smem;
    int*   rnk   = smem + N_EP;
    int*   deg_s = smem + 2 * N_EP;
    float* fcnt  = (float*)(smem + 3 * N_EP);
    float* fsx   = (float*)(smem + 4 * N_EP);
    float* fsy   = (float*)(smem + 5 * N_EP);
    float* fss   = (float*)(smem + 6 * N_EP);
    __shared__ int wsum[16];
    __shared__ int changed;

    int t = threadIdx.x;
    int lane = t & 63, wv = t >> 6;
    for (int i = t; i < N_EP; i += 1024) {
        lab[i] = i;
        deg_s[i] = deg[i];
        fcnt[i] = 0.f; fsx[i] = 0.f; fsy[i] = 0.f; fss[i] = 0.f;
    }
    // min-label propagation with pointer jumping (pure LDS for deg==0 points)
    for (int it = 0; it < 64; ++it) {
        __syncthreads();
        if (t == 0) changed = 0;
        __syncthreads();
        int f = 0;
        for (int i = t; i < N_EP; i += 1024) {
            int m = lab[i];
            int dg = deg_s[i];
            const int* nb = nbr + i * MAXNBR;
            for (int q = 0; q < dg; q++) m = min(m, lab[nb[q]]);
            m = min(m, lab[m]);           // pointer jump (lab[k] <= k invariant)
            if (m < lab[i]) { lab[i] = m; f = 1; }
        }
        if (f) atomicOr(&changed, 1);
        __syncthreads();
        if (changed == 0) break;
    }
    __syncthreads();
    // presence bitmap of roots -> dense rank via exclusive scan
    for (int i = t; i < N_EP; i += 1024) rnk[i] = 0;
    __syncthreads();
    for (int i = t; i < N_EP; i += 1024) rnk[lab[i]] = 1;
    __syncthreads();
    {
        int b4 = t * 4;
        int a0 = rnk[b4], a1 = rnk[b4 + 1], a2 = rnk[b4 + 2], a3 = rnk[b4 + 3];
        int s = a0 + a1 + a2 + a3;
        int v = s;
        for (int off = 1; off < 64; off <<= 1) {
            int u = __shfl_up(v, off);
            if (lane >= off) v += u;
        }
        if (lane == 63) wsum[wv] = v;
        __syncthreads();
        if (wv == 0 && lane < 16) {
            int w = wsum[lane];
            for (int off = 1; off < 16; off <<= 1) {
                int u = __shfl_up(w, off);
                if (lane >= off) w += u;
            }
            wsum[lane] = w;
        }
        __syncthreads();
        int excl = ((wv == 0) ? 0 : wsum[wv - 1]) + v - s;
        rnk[b4] = excl;
        rnk[b4 + 1] = excl + a0;
        rnk[b4 + 2] = excl + a0 + a1;
        rnk[b4 + 3] = excl + a0 + a1 + a2;
    }
    __syncthreads();
    // relabel + LDS segment sums
    for (int i = t; i < N_EP; i += 1024) {
        int c = rnk[lab[i]];
        out_lji[i] = (float)c;
        float2 p = ep[i];
        atomicAdd(&fcnt[c], 1.f);
        atomicAdd(&fsx[c], p.x);
        atomicAdd(&fsy[c], p.y);
        atomicAdd(&fss[c], ws_ls[i >> 1]);
        lab[i] = c;                       // lab now holds cluster id
    }
    __syncthreads();
    // segment means -> junction outputs
    for (int j = t; j < N_EP; j += 1024) {
        float cm = fmaxf(fcnt[j], 1.f);
        float jx = fsx[j] / cm, jy = fsy[j] / cm;
        fsx[j] = jx; fsy[j] = jy;
        junc[2 * j] = jx; junc[2 * j + 1] = jy;
        out_pts[2 * j] = jx; out_pts[2 * j + 1] = jy;
        out_sc[j] = fss[j] / cm;
    }
    __syncthreads();
    // new_lines = junctions[clusters]
    for (int e = t; e < N_EP; e += 1024) {
        int c = lab[e];
        out_nl[2 * e] = fsx[c];
        out_nl[2 * e + 1] = fsy[c];
    }
}

// ============================================================================
// K_SAMP: blocks [0,256): bilinear sample, 1 block/channel, plane in LDS
// (input read exactly once), no atomics. Blocks [256,384): float4 masked
// copy of keypoint descriptors (needs only keep + desc).
// ============================================================================
__global__ __launch_bounds__(1024) void k_samp(const float* __restrict__ ad,
                                               const float* __restrict__ junc,
                                               const float* __restrict__ desc,
                                               const int* __restrict__ keep,
                                               float* __restrict__ v_ws,
                                               float* __restrict__ out_desc) {
    __shared__ float plane[HC_ * WC_];   // 64 KB
    int b = blockIdx.x, t = threadIdx.x;
    if (b < CCH) {
        int c = b;
        const float4* s4 = (const float4*)(ad + c * (HC_ * WC_));
        float4* p4 = (float4*)plane;
        #pragma unroll
        for (int i = 0; i < 4; ++i) p4[t + i * 1024] = s4[t + i * 1024];
        __syncthreads();
        const float2* j2 = (const float2*)junc;
        #pragma unroll
        for (int k = 0; k < 4; ++k) {
            int m = t + k * 1024;
            float2 pj = j2[m];
            float x = (pj.x - 3.5f) * (127.0f / 1019.5f);
            float y = (pj.y - 3.5f) * (127.0f / 1019.5f);
            float x0f = fminf(fmaxf(floorf(x), 0.f), WC_ - 1);
            float y0f = fminf(fmaxf(floorf(y), 0.f), HC_ - 1);
            float x1f = fminf(x0f + 1.f, WC_ - 1);
            float y1f = fminf(y0f + 1.f, HC_ - 1);
            float wx = x - x0f, wy = y - y0f;
            int x0 = (int)x0f, x1 = (int)x1f, y0 = (int)y0f, y1 = (int)y1f;
            float v = plane[y0 * WC_ + x0] * (1.f - wx) * (1.f - wy)
                    + plane[y0 * WC_ + x1] * wx * (1.f - wy)
                    + plane[y1 * WC_ + x0] * (1.f - wx) * wy
                    + plane[y1 * WC_ + x1] * wx * wy;
            v_ws[c * N_EP + m] = v;
        }
    } else {
        int gid = (b - CCH) * 1024 + t;      // 131072 float4 groups
        int c = gid >> 9;                    // 512 groups per channel
        int k4 = (gid & 511) * 4;
        float4 d = *(const float4*)(desc + c * KPTS + k4);
        float4 o;
        o.x = keep[k4]     ? d.x : 0.f;
        o.y = keep[k4 + 1] ? d.y : 0.f;
        o.z = keep[k4 + 2] ? d.z : 0.f;
        o.w = keep[k4 + 3] ? d.w : 0.f;
        *(float4*)(out_desc + c * NPTS_ALL + N_EP + k4) = o;
    }
}

// ============================================================================
// K_EPI: 64 blocks; 256ch x 64junc LDS tile — column norms + normalize,
// fully coalesced, no atomics.
// ============================================================================
__global__ __launch_bounds__(256) void k_epi(const float* __restrict__ v_ws,
                                             float* __restrict__ out_desc) {
    __shared__ float tile[CCH][64];
    __shared__ float partial[4][64];
    __shared__ float inv[64];
    int b = blockIdx.x, t = threadIdx.x;
    int m0 = b * 64;
    int q = t >> 6, ml = t & 63;
    for (int cc = 0; cc < 64; ++cc) {
        int c = cc * 4 + q;
        tile[c][ml] = v_ws[c * N_EP + m0 + ml];
    }
    __syncthreads();
    float s = 0.f;
    for (int c = q * 64; c < q * 64 + 64; ++c) {
        float v = tile[c][ml];
        s += v * v;
    }
    partial[q][ml] = s;
    __syncthreads();
    if (t < 64) {
        float tot = partial[0][t] + partial[1][t] + partial[2][t] + partial[3][t];
        inv[t] = 1.f / fmaxf(sqrtf(tot), 1e-12f);
    }
    __syncthreads();
    for (int cc = 0; cc < 64; ++cc) {
        int c = cc * 4 + q;
        out_desc[c * NPTS_ALL + m0 + ml] = tile[c][ml] * inv[ml];
    }
}

extern "C" void kernel_launch(void* const* d_in, const int* in_sizes, int n_in,
                              void* d_out, int out_size, void* d_ws, size_t ws_size,
                              hipStream_t stream) {
    const float* lines    = (const float*)d_in[0];   // (1,2048,2,2) == endpoints (4096,2)
    const float* lscores  = (const float*)d_in[1];   // (1,2048)
    const float* kpts     = (const float*)d_in[2];   // (1,2048,2)
    const float* kscores  = (const float*)d_in[3];   // (1,2048)
    const float* descs    = (const float*)d_in[4];   // (1,256,2048)
    const float* alldesc  = (const float*)d_in[5];   // (1,256,128,128)
    float* out = (float*)d_out;

    float* wf   = (float*)d_ws;
    int*   wi   = (int*)d_ws;
    float* ws_ls = wf + W_LS;
    int*   deg   = wi + W_DEG;
    int*   nbr   = wi + W_NBR;
    int*   keep  = wi + W_KEEP;
    float* junc  = wf + W_JUNC;
    float* v_ws  = wf + W_V;

    k_front<<<N_EP + KPTS + 1, 256, 0, stream>>>(
        (const float2*)lines, (const float2*)kpts, kscores, lscores,
        deg, nbr, keep, ws_ls, out + O_PTS, out + O_SC, out + O_LS);

    size_t lds_bytes = (size_t)(7 * N_EP) * sizeof(int);   // 112 KB
    k_cluster<<<1, 1024, lds_bytes, stream>>>(
        (const float2*)lines, deg, nbr, ws_ls, junc,
        out + O_PTS, out + O_SC, out + O_NL, out + O_LJI);

    k_samp<<<CCH + 128, 1024, 0, stream>>>(alldesc, junc, descs, keep, v_ws,
                                           out + O_DESC);

    k_epi<<<64, 256, 0, stream>>>(v_ws, out + O_DESC);
}